// Round 15
// baseline (171.562 us; speedup 1.0000x reference)
//
#include <hip/hip_runtime.h>
#include <math.h>

#define NQ   12
#define NL   4
#define BLK  256

typedef float v4f  __attribute__((ext_vector_type(4)));
typedef __fp16 v8h __attribute__((ext_vector_type(8)));

// Inverse CNOT-ring map (apply CNOTs in forward order). GF(2)-linear.
// final[i] = preC[sigma(i)]  =>  store preC[j] at slot sigma_inv(j).
__device__ __forceinline__ constexpr int sigma_inv_c(int i) {
    int j = i;
    for (int c = 0; c < NQ; ++c) {
        int t = (c + 1) % NQ;
        int cb = (j >> (NQ - 1 - c)) & 1;
        j ^= cb << (NQ - 1 - t);
    }
    return j;
}

// LDS halfword address of (part p, column CC(8b), row r(4b)) in one 16KB buffer.
// line(10b) = p<<9 | CC<<1 | r>>3, swizzle: bits 2..0 ^= bits 8..6; hw = r&7.
__device__ __forceinline__ int haddr(int p, int CC, int r) {
    int line = (p << 9) | (CC << 1) | (r >> 3);
    line ^= (line >> 6) & 7;
    return line * 8 + (r & 7);
}

__device__ __forceinline__ unsigned pk2(float a, float b) {
    return __builtin_bit_cast(unsigned, __builtin_amdgcn_cvt_pkrtz(a, b));
}

// Per-lane, per-phase B-fragment build from the fused 2x2 gate table (LDS).
// U16[n][r] = prod_p U_{wire wbase+(3-p)}[n_p][r_p]; lane holds k=g*8+j:
// k<16 -> B1=Re, B2=Im (rows r=k); k>=16 -> B1=-Im, B2=Re (rows r=k-16).
// Gate row layout {00r,00i,01r,01i,10r,10i,11r,11i}: float4 at +nb*4 gives
// both rb entries for this lane's nb.
__device__ __forceinline__ void build_frag(const float* gt, int l, int wbase,
                                           int nn, int g, v8h* B1, v8h* B2) {
    const int rtop = g & 1;
    const float4 e3 = *(const float4*)(gt + (l * NQ + wbase + 0) * 8 + ((nn >> 3) & 1) * 4);
    const float4 e2 = *(const float4*)(gt + (l * NQ + wbase + 1) * 8 + ((nn >> 2) & 1) * 4);
    const float4 e1 = *(const float4*)(gt + (l * NQ + wbase + 2) * 8 + ((nn >> 1) & 1) * 4);
    const float4 e0 = *(const float4*)(gt + (l * NQ + wbase + 3) * 8 + (nn & 1) * 4);
    const float f3r = rtop ? e3.z : e3.x, f3i = rtop ? e3.w : e3.y;
    float Pr[2], Pi[2];
    Pr[0] = f3r * e2.x - f3i * e2.y;  Pi[0] = f3r * e2.y + f3i * e2.x;
    Pr[1] = f3r * e2.z - f3i * e2.w;  Pi[1] = f3r * e2.w + f3i * e2.z;
    float Qr[4], Qi[4];
    Qr[0] = e1.x * e0.x - e1.y * e0.y;  Qi[0] = e1.x * e0.y + e1.y * e0.x;
    Qr[1] = e1.x * e0.z - e1.y * e0.w;  Qi[1] = e1.x * e0.w + e1.y * e0.z;
    Qr[2] = e1.z * e0.x - e1.w * e0.y;  Qi[2] = e1.z * e0.y + e1.w * e0.x;
    Qr[3] = e1.z * e0.z - e1.w * e0.w;  Qi[3] = e1.z * e0.w + e1.w * e0.z;
    const bool re_part = (g < 2);
    #pragma unroll
    for (int j = 0; j < 8; ++j) {
        const int m2 = (j >> 2) & 1, m10 = j & 3;
        const float vr = Pr[m2] * Qr[m10] - Pi[m2] * Qi[m10];
        const float vi = Pr[m2] * Qi[m10] + Pi[m2] * Qr[m10];
        (*B1)[j] = (__fp16)(re_part ? vr : -vi);
        (*B2)[j] = (__fp16)(re_part ? vi :  vr);
    }
}

#define READ_FRAGS(SRC)                                                     \
    _Pragma("unroll")                                                       \
    for (int q = 0; q < 4; ++q)                                             \
        af[q] = __builtin_bit_cast(v8h, *(const uint4*)&sh[(SRC) +          \
                    haddr(p, (wv << 6) | (q << 4) | nn, (g & 1) * 8)]);

#define MFMA_PHASE()                                                        \
    _Pragma("unroll")                                                       \
    for (int q = 0; q < 4; ++q) {                                           \
        d1[q] = __builtin_amdgcn_mfma_f32_16x16x32_f16(af[q], b1, zf, 0, 0, 0); \
        d2[q] = __builtin_amdgcn_mfma_f32_16x16x32_f16(af[q], b2, zf, 0, 0, 0); \
    }

#define WRITE_COLS(DST)                                                     \
    _Pragma("unroll")                                                       \
    for (int q = 0; q < 4; ++q) {                                           \
        const int CCn = (nn << 4) | (wv << 2) | q;                          \
        *(uint2*)&sh[(DST) + haddr(0, CCn, 4 * g)] =                        \
            make_uint2(pk2(d1[q].x, d1[q].y), pk2(d1[q].z, d1[q].w));       \
        *(uint2*)&sh[(DST) + haddr(1, CCn, 4 * g)] =                        \
            make_uint2(pk2(d2[q].x, d2[q].y), pk2(d2[q].z, d2[q].w));       \
    }

#define WRITE_SIGMA(DST)                                                    \
    _Pragma("unroll")                                                       \
    for (int q = 0; q < 4; ++q) {                                           \
        const int iq = ifix ^ sigma_inv_c(q << 4);                          \
        _Pragma("unroll")                                                   \
        for (int rg = 0; rg < 4; ++rg) {                                    \
            const int ii = iq ^ sigma_inv_c(rg);                            \
            sh[(DST) + haddr(0, ii >> 4, ii & 15)] = (__fp16)d1[q][rg];     \
            sh[(DST) + haddr(1, ii >> 4, ii & 15)] = (__fp16)d2[q][rg];     \
        }                                                                   \
    }

__global__ __launch_bounds__(BLK) void qsim_kernel(
    const float* __restrict__ x,      // (B, 12)
    const float* __restrict__ qw,     // (144,)
    const float* __restrict__ dw,     // (12, 12)
    const float* __restrict__ db,     // (12,)
    float* __restrict__ out)          // (B, 12)
{
    __shared__ __align__(16) __fp16 sh[16384];       // two 16KB ping-pong buffers
    __shared__ __align__(16) float gtab[NL * NQ * 8]; // fused 2x2 gates (persists)
    float* xv    = (float*)sh;
    float* enc_c = (float*)sh + 16;
    float* enc_s = (float*)sh + 32;
    float* red   = (float*)sh;

    const int tid  = threadIdx.x;
    const int lane = tid & 63;
    const int wv   = tid >> 6;
    const int s    = blockIdx.x;
    const int nn = lane & 15, g = lane >> 4, p = g >> 1;
    const v4f zf = {0.f, 0.f, 0.f, 0.f};

    // ---- fused RZ*RY*RX 2x2 gates into LDS table (lanes 0..47, once) ----
    if (tid < NL * NQ) {
        const int pp = (tid / NQ) * 3 * NQ + 3 * (tid % NQ);
        float t1 = qw[pp], t2 = qw[pp + 1], t3 = qw[pp + 2];
        float a, b, c, d, gr, h;
        sincosf(0.5f * t1, &b, &a);   // RX
        sincosf(0.5f * t2, &d, &c);   // RY
        sincosf(0.5f * t3, &h, &gr);  // RZ
        float m00r =  c * a, m00i =  d * b;
        float m01r = -d * a, m01i = -c * b;
        float m10r =  d * a, m10i = -c * b;
        float m11r =  c * a, m11i = -d * b;
        float* gg = &gtab[tid * 8];
        gg[0] = gr * m00r + h * m00i;  gg[1] = gr * m00i - h * m00r;
        gg[2] = gr * m01r + h * m01i;  gg[3] = gr * m01i - h * m01r;
        gg[4] = gr * m10r - h * m10i;  gg[5] = gr * m10i + h * m10r;
        gg[6] = gr * m11r - h * m11i;  gg[7] = gr * m11i + h * m11r;
    }
    if (tid < NQ) xv[tid] = x[s * NQ + tid];
    __syncthreads();
    if (tid < NQ) {
        float ss = 0.f;
        #pragma unroll
        for (int j = 0; j < NQ; ++j) ss += xv[j] * xv[j];
        float inv = rsqrtf(fmaxf(ss, 1e-12f));
        float mx = 0.f;
        #pragma unroll
        for (int j = 0; j < NQ; ++j) mx = fmaxf(mx, fabsf(xv[j] * inv));
        float ang = 3.14159265358979323846f * (xv[tid] * inv) / (mx + 1e-8f);
        float cc, sn;
        sincosf(0.5f * ang, &sn, &cc);
        enc_c[tid] = cc; enc_s[tid] = sn;
    }
    __syncthreads();

    // ---- product-state init directly as phase-A A-fragments ----
    v8h af[4];
    {
        #define PICK(W, B) ((B) ? enc_s[W] : enc_c[W])
        if (g < 2) {
            float R[8];
            #pragma unroll
            for (int j = 0; j < 8; ++j) {
                const int r = g * 8 + j;
                R[j] = PICK(8, (r >> 3) & 1) * PICK(9, (r >> 2) & 1)
                     * PICK(10, (r >> 1) & 1) * PICK(11, r & 1);
            }
            const float Pfix = PICK(0, (wv >> 1) & 1) * PICK(1, wv & 1)
                             * PICK(4, (nn >> 3) & 1) * PICK(5, (nn >> 2) & 1)
                             * PICK(6, (nn >> 1) & 1) * PICK(7, nn & 1);
            #pragma unroll
            for (int q = 0; q < 4; ++q) {
                const float Pq = Pfix * PICK(2, (q >> 1) & 1) * PICK(3, q & 1);
                #pragma unroll
                for (int j = 0; j < 8; ++j) af[q][j] = (__fp16)(Pq * R[j]);
            }
        } else {
            const uint4 uz = {0u, 0u, 0u, 0u};
            #pragma unroll
            for (int q = 0; q < 4; ++q) af[q] = __builtin_bit_cast(v8h, uz);
        }
        #undef PICK
    }
    __syncthreads();   // enc reads done before buffer 0 is overwritten

    const int ifix = sigma_inv_c((nn << 8) | (wv << 6) | (g << 2));

    v4f d1[4], d2[4];
    v8h b1, b2;
    #pragma unroll 1
    for (int l = 0; l < NL; ++l) {
        const int XA = (l & 1) * 8192;
        const int XB = 8192 - XA;

        build_frag(gtab, l, 8, nn, g, &b1, &b2);
        if (l > 0) { READ_FRAGS(XB) }
        MFMA_PHASE()                      // wires 8..11
        WRITE_COLS(XA)
        __syncthreads();

        build_frag(gtab, l, 4, nn, g, &b1, &b2);
        READ_FRAGS(XA)
        MFMA_PHASE()                      // wires 4..7
        WRITE_COLS(XB)
        __syncthreads();

        build_frag(gtab, l, 0, nn, g, &b1, &b2);
        READ_FRAGS(XB)
        MFMA_PHASE()                      // wires 0..3
        if (l < NL - 1) {
            WRITE_SIGMA(XA)
            __syncthreads();
        }
    }

    // ---- Z expectations straight from final D-regs (sigma via index) ----
    float vals[NQ];
    #pragma unroll
    for (int w = 0; w < NQ; ++w) vals[w] = 0.f;
    #pragma unroll
    for (int q = 0; q < 4; ++q) {
        const int iq = ifix ^ sigma_inv_c(q << 4);
        #pragma unroll
        for (int rg = 0; rg < 4; ++rg) {
            const int ii = iq ^ sigma_inv_c(rg);
            const float pr = d1[q][rg] * d1[q][rg] + d2[q][rg] * d2[q][rg];
            #pragma unroll
            for (int w = 0; w < NQ; ++w)
                vals[w] += ((ii >> (11 - w)) & 1) ? -pr : pr;
        }
    }
    #pragma unroll
    for (int m = 1; m <= 32; m <<= 1) {
        #pragma unroll
        for (int w = 0; w < NQ; ++w) vals[w] += __shfl_xor(vals[w], m);
    }
    __syncthreads();   // all waves done with sh before red alias is written
    if (lane == 0) {
        #pragma unroll
        for (int w = 0; w < NQ; ++w) red[wv * NQ + w] = vals[w];
    }
    __syncthreads();
    if (tid < NQ)
        red[48 + tid] = red[tid] + red[NQ + tid] + red[2 * NQ + tid] + red[3 * NQ + tid];
    __syncthreads();
    if (tid < NQ) {
        float v = db[tid];
        #pragma unroll
        for (int w = 0; w < NQ; ++w) v += red[48 + w] * dw[w * NQ + tid];
        out[s * NQ + tid] = tanhf(v);
    }
}

extern "C" void kernel_launch(void* const* d_in, const int* in_sizes, int n_in,
                              void* d_out, int out_size, void* d_ws, size_t ws_size,
                              hipStream_t stream) {
    const float* x  = (const float*)d_in[0];
    const float* qw = (const float*)d_in[1];
    const float* dw = (const float*)d_in[2];
    const float* db = (const float*)d_in[3];
    float* out = (float*)d_out;
    int batch = in_sizes[0] / NQ;
    qsim_kernel<<<batch, BLK, 0, stream>>>(x, qw, dw, db, out);
}

// Round 16
// 121.103 us; speedup vs baseline: 1.4167x; 1.4167x over previous
//
#include <hip/hip_runtime.h>
#include <math.h>

#define NQ   12
#define NL   4
#define BLK  256

typedef float v4f  __attribute__((ext_vector_type(4)));
typedef __fp16 v8h __attribute__((ext_vector_type(8)));

// Inverse CNOT-ring map (apply CNOTs in forward order). GF(2)-linear.
// final[i] = preC[sigma(i)]  =>  store preC[j] at slot sigma_inv(j).
__device__ __forceinline__ constexpr int sigma_inv_c(int i) {
    int j = i;
    for (int c = 0; c < NQ; ++c) {
        int t = (c + 1) % NQ;
        int cb = (j >> (NQ - 1 - c)) & 1;
        j ^= cb << (NQ - 1 - t);
    }
    return j;
}

// State buffer: amp (col CC(8b), row r(4b)) as interleaved (re,im) f16 pair.
// 16B line = 4 amps: line = CC*4 + (r>>2); hw-in-line = (r&3)*2 + part.
// Line swizzle: bits 2..0 ^= bits 5..3 ^ bits 9..7 — verified <=2-way for
// both the fragment reads (nn in C-low) and column writes (nn in C-high).
__device__ __forceinline__ constexpr int lswz(int l) {
    return l ^ (((l >> 3) ^ (l >> 7)) & 7);
}

__device__ __forceinline__ unsigned pk2(float a, float b) {
    return __builtin_bit_cast(unsigned, __builtin_amdgcn_cvt_pkrtz(a, b));
}

// ---- pre-kernel: fused gates -> 12 U16 matrices -> f16 B-fragments in d_ws ----
// K-interleaved rows: B1[2r]=Ur^T row r, B1[2r+1]=-Ui^T; B2[2r]=Ui^T, B2[2r+1]=Ur^T.
// Fragment lane order: value B[k][n] at hw ((k>>3)*16+n)*8+(k&7).
__device__ __forceinline__ int fslot(int k, int n) {
    return ((k >> 3) * 16 + n) * 8 + (k & 7);
}

__global__ __launch_bounds__(BLK) void gate_kernel(
    const float* __restrict__ qw, __fp16* __restrict__ gout)
{
    __shared__ float G[NL * NQ][8];
    const int t = threadIdx.x;
    if (t < NL * NQ) {
        const int p = (t / NQ) * 3 * NQ + 3 * (t % NQ);
        float t1 = qw[p], t2 = qw[p + 1], t3 = qw[p + 2];
        float a, b, c, d, gr, h;
        sincosf(0.5f * t1, &b, &a);   // RX
        sincosf(0.5f * t2, &d, &c);   // RY
        sincosf(0.5f * t3, &h, &gr);  // RZ
        float m00r =  c * a, m00i =  d * b;
        float m01r = -d * a, m01i = -c * b;
        float m10r =  d * a, m10i = -c * b;
        float m11r =  c * a, m11i = -d * b;
        float* g = G[t];
        g[0] = gr * m00r + h * m00i;  g[1] = gr * m00i - h * m00r;
        g[2] = gr * m01r + h * m01i;  g[3] = gr * m01i - h * m01r;
        g[4] = gr * m10r - h * m10i;  g[5] = gr * m10i + h * m10r;
        g[6] = gr * m11r - h * m11i;  g[7] = gr * m11i + h * m11r;
    }
    __syncthreads();
    const int n = t & 15, r = t >> 4;
    for (int mat = 0; mat < 12; ++mat) {
        const int layer = mat / 3, ph = mat % 3;
        const int wbase = (ph == 0) ? 8 : (ph == 1) ? 4 : 0;
        float cr = 1.f, ci = 0.f;
        #pragma unroll
        for (int b = 0; b < 4; ++b) {         // bit (3-b) of row <-> wire wbase+b
            const float* g = G[layer * NQ + wbase + b];
            const int rb = (r >> (3 - b)) & 1, nb = (n >> (3 - b)) & 1;
            const float er = g[(nb * 2 + rb) * 2], ei = g[(nb * 2 + rb) * 2 + 1];
            const float xr = cr * er - ci * ei, xi = cr * ei + ci * er;
            cr = xr; ci = xi;
        }
        __fp16* b1 = gout + (mat * 2 + 0) * 512;
        __fp16* b2 = gout + (mat * 2 + 1) * 512;
        b1[fslot(2 * r, n)]     = (__fp16)cr;
        b1[fslot(2 * r + 1, n)] = (__fp16)(-ci);
        b2[fslot(2 * r, n)]     = (__fp16)ci;
        b2[fslot(2 * r + 1, n)] = (__fp16)cr;
    }
}

// A-fragment: lane (nn,g) k=8g..8g+7 -> amps r=4g..4g+3, (re,im) interleaved.
#define READ_FRAGS(SRC)                                                     \
    _Pragma("unroll")                                                       \
    for (int q = 0; q < 4; ++q)                                             \
        af[q] = __builtin_bit_cast(v8h, *(const uint4*)&sh[(SRC) +          \
                    lswz((((wv) << 6) | (q << 4) | nn) * 4 + g) * 8]);

#define MFMA_PHASE(MAT)                                                     \
    { const v8h b1 = gf[((MAT) * 2 + 0) * 64 + lane];                       \
      const v8h b2 = gf[((MAT) * 2 + 1) * 64 + lane];                       \
      _Pragma("unroll")                                                     \
      for (int q = 0; q < 4; ++q) {                                         \
          d1[q] = __builtin_amdgcn_mfma_f32_16x16x32_f16(af[q], b1, zf, 0, 0, 0); \
          d2[q] = __builtin_amdgcn_mfma_f32_16x16x32_f16(af[q], b2, zf, 0, 0, 0); \
      } }

// Element (q,rg): new row' = 4g+rg, col' = nn<<4|wv<<2|q -> one b128 per q.
#define WRITE_COLS(DST)                                                     \
    _Pragma("unroll")                                                       \
    for (int q = 0; q < 4; ++q) {                                           \
        const int CCn = (nn << 4) | (wv << 2) | q;                          \
        *(uint4*)&sh[(DST) + lswz(CCn * 4 + g) * 8] =                       \
            make_uint4(pk2(d1[q].x, d2[q].x), pk2(d1[q].y, d2[q].y),        \
                       pk2(d1[q].z, d2[q].z), pk2(d1[q].w, d2[q].w));       \
    }

// Phase-C out -> phase-A container with sigma folded in: b32 (re,im) scatter.
#define WRITE_SIGMA(DST)                                                    \
    _Pragma("unroll")                                                       \
    for (int q = 0; q < 4; ++q) {                                           \
        const int iq = ifix ^ sigma_inv_c(q << 4);                          \
        _Pragma("unroll")                                                   \
        for (int rg = 0; rg < 4; ++rg) {                                    \
            const int ii = iq ^ sigma_inv_c(rg);                            \
            *(unsigned*)&sh[(DST) + lswz(ii >> 2) * 8 + (ii & 3) * 2] =     \
                pk2(d1[q][rg], d2[q][rg]);                                  \
        }                                                                   \
    }

__global__ __launch_bounds__(BLK) void qsim_kernel(
    const float* __restrict__ x,      // (B, 12)
    const __fp16* __restrict__ gates, // 12 x (B1,B2) f16 fragment tables (d_ws)
    const float* __restrict__ dw,     // (12, 12)
    const float* __restrict__ db,     // (12,)
    float* __restrict__ out)          // (B, 12)
{
    __shared__ __align__(16) __fp16 sh[16384];   // two 16KB ping-pong buffers
    float* xv    = (float*)sh;
    float* enc_c = (float*)sh + 16;
    float* enc_s = (float*)sh + 32;
    float* red   = (float*)sh;

    const int tid  = threadIdx.x;
    const int lane = tid & 63;
    const int wv   = tid >> 6;
    const int s    = blockIdx.x;
    const int nn = lane & 15, g = lane >> 4;
    const v8h* gf = (const v8h*)gates;
    const v4f zf = {0.f, 0.f, 0.f, 0.f};

    if (tid < NQ) xv[tid] = x[s * NQ + tid];
    __syncthreads();
    if (tid < NQ) {
        float ss = 0.f;
        #pragma unroll
        for (int j = 0; j < NQ; ++j) ss += xv[j] * xv[j];
        float inv = rsqrtf(fmaxf(ss, 1e-12f));
        float mx = 0.f;
        #pragma unroll
        for (int j = 0; j < NQ; ++j) mx = fmaxf(mx, fabsf(xv[j] * inv));
        float ang = 3.14159265358979323846f * (xv[tid] * inv) / (mx + 1e-8f);
        float cc, sn;
        sincosf(0.5f * ang, &sn, &cc);
        enc_c[tid] = cc; enc_s[tid] = sn;
    }
    __syncthreads();

    // ---- product-state init as phase-A A-fragments (interleaved re/im) ----
    v8h af[4];
    {
        #define PICK(W, B) ((B) ? enc_s[W] : enc_c[W])
        float R4[4];
        #pragma unroll
        for (int t = 0; t < 4; ++t) {
            const int r = 4 * g + t;
            R4[t] = PICK(8, (r >> 3) & 1) * PICK(9, (r >> 2) & 1)
                  * PICK(10, (r >> 1) & 1) * PICK(11, r & 1);
        }
        const float Pfix = PICK(0, (wv >> 1) & 1) * PICK(1, wv & 1)
                         * PICK(4, (nn >> 3) & 1) * PICK(5, (nn >> 2) & 1)
                         * PICK(6, (nn >> 1) & 1) * PICK(7, nn & 1);
        #pragma unroll
        for (int q = 0; q < 4; ++q) {
            const float Pq = Pfix * PICK(2, (q >> 1) & 1) * PICK(3, q & 1);
            #pragma unroll
            for (int t = 0; t < 4; ++t) {
                af[q][2 * t]     = (__fp16)(Pq * R4[t]);
                af[q][2 * t + 1] = (__fp16)0.f;
            }
        }
        #undef PICK
    }
    __syncthreads();   // enc reads done before buffer 0 is overwritten

    const int ifix = sigma_inv_c((nn << 8) | (wv << 6) | (g << 2));

    v4f d1[4], d2[4];
    #pragma unroll 1
    for (int l = 0; l < NL; ++l) {
        const int XA = (l & 1) * 8192;
        const int XB = 8192 - XA;

        if (l > 0) { READ_FRAGS(XB) }
        MFMA_PHASE(l * 3 + 0)             // wires 8..11
        WRITE_COLS(XA)
        __syncthreads();

        READ_FRAGS(XA)
        MFMA_PHASE(l * 3 + 1)             // wires 4..7
        WRITE_COLS(XB)
        __syncthreads();

        READ_FRAGS(XB)
        MFMA_PHASE(l * 3 + 2)             // wires 0..3
        if (l < NL - 1) {
            WRITE_SIGMA(XA)
            __syncthreads();
        }
    }

    // ---- Z expectations via 16-pt Walsh-Hadamard over (q,rg) ----
    // vals[w] = t_w * WHT(pr)[f_w]: sigma_inv is GF(2)-linear, so the per-
    // element sign is a character of the 4-bit (q,rg) group.
    float pr[16];
    #pragma unroll
    for (int q = 0; q < 4; ++q)
        #pragma unroll
        for (int rg = 0; rg < 4; ++rg)
            pr[q * 4 + rg] = d1[q][rg] * d1[q][rg] + d2[q][rg] * d2[q][rg];
    #pragma unroll
    for (int st = 1; st < 16; st <<= 1) {
        #pragma unroll
        for (int i = 0; i < 16; ++i) {
            if (!(i & st)) {
                const float a = pr[i], b = pr[i ^ st];
                pr[i] = a + b; pr[i ^ st] = a - b;
            }
        }
    }
    float vals[NQ];
    #pragma unroll
    for (int w = 0; w < NQ; ++w) {
        const int sb = 11 - w;
        const int f = (((sigma_inv_c(0x20) >> sb) & 1) << 3)
                    | (((sigma_inv_c(0x10) >> sb) & 1) << 2)
                    | (((sigma_inv_c(2)    >> sb) & 1) << 1)
                    |  ((sigma_inv_c(1)    >> sb) & 1);
        const float v = pr[f];
        vals[w] = ((ifix >> sb) & 1) ? -v : v;
    }
    #pragma unroll
    for (int m = 1; m <= 32; m <<= 1) {
        #pragma unroll
        for (int w = 0; w < NQ; ++w) vals[w] += __shfl_xor(vals[w], m);
    }
    __syncthreads();   // all waves done with sh before red alias is written
    if (lane == 0) {
        #pragma unroll
        for (int w = 0; w < NQ; ++w) red[wv * NQ + w] = vals[w];
    }
    __syncthreads();
    if (tid < NQ)
        red[48 + tid] = red[tid] + red[NQ + tid] + red[2 * NQ + tid] + red[3 * NQ + tid];
    __syncthreads();
    if (tid < NQ) {
        float v = db[tid];
        #pragma unroll
        for (int w = 0; w < NQ; ++w) v += red[48 + w] * dw[w * NQ + tid];
        out[s * NQ + tid] = tanhf(v);
    }
}

extern "C" void kernel_launch(void* const* d_in, const int* in_sizes, int n_in,
                              void* d_out, int out_size, void* d_ws, size_t ws_size,
                              hipStream_t stream) {
    const float* x  = (const float*)d_in[0];
    const float* qw = (const float*)d_in[1];
    const float* dw = (const float*)d_in[2];
    const float* db = (const float*)d_in[3];
    float* out = (float*)d_out;
    __fp16* gates = (__fp16*)d_ws;          // 12 x 2 x 512 f16 = 24576 B
    int batch = in_sizes[0] / NQ;
    gate_kernel<<<1, BLK, 0, stream>>>(qw, gates);
    qsim_kernel<<<batch, BLK, 0, stream>>>(x, gates, dw, db, out);
}